// Round 11
// baseline (800.066 us; speedup 1.0000x reference)
//
#include <hip/hip_runtime.h>

// Problem constants (match reference)
#define BATCHN 32
#define NCELL  4096
#define BN     (BATCHN * NCELL)

// Round 11: single cooperative launch + NEIGHBOR-flag sync (no grid.sync).
// Model (fits R1-R10): dur = 10 x (OH + K), OH ~9.5us per dependent
// dispatch, K ~5.5us kernel. 95us of R10's 151.5 is dispatch overhead.
// R9 showed grid.sync() costs ~150us/sync on 1024 blocks; here each wave
// syncs only with its 2 chunk neighbors via device-scope release/acquire
// flags in d_ws (the guide's sanctioned cross-XCD pattern), then halo
// lanes reload from the trajectory plane written this epoch. Owned lanes
// keep state in registers. Math identical to R10 (DPP exchange, packed
// evals) -> absmax expected bit-identical (0.00390625).
constexpr int OWN    = 128;
constexpr int HALO   = 64;
constexpr int CPL    = 4;                  // cells per lane
constexpr int KSTEP  = 60;                 // steps per sync epoch (< HALO)
constexpr int CHUNKS = NCELL / OWN;        // 32
constexpr int NWAVES = CHUNKS * BATCHN;    // 1024

typedef float v2f __attribute__((ext_vector_type(2)));

// hf = 0.5*f_real(u), ha = 0.5*|f_real'(u)| — monomial expansion, 0.5
// pre-folded (verified vs reference at u=1: f=1,f'=0; u=0.5: f=0.710286,
// f'=1.085938). Flux uses 0.5*max(a,b) == max(0.5a,0.5b) exactly.
__device__ __forceinline__ void eval2(v2f u, v2f& hf, v2f& ha) {
    v2f u2 = u * u;
    v2f u3 = u2 * u;
    v2f p1 = u * 0.3125f + 0.75f;
    v2f A  = u * p1;                               // 0.75u + 0.3125u^2
    v2f p2 = u * 0.625f + (-1.0833333333333333f);  // -13/12 + 0.625u
    v2f B  = u3 * p2 + A;
    v2f u6 = u3 * u3;
    hf = u6 * (-0.10416666666666667f) + B;         // -5/48 u^6
    v2f p3 = u * 0.625f + 0.75f;
    v2f p4 = u * 2.5f + (-3.25f);
    v2f C  = u2 * p4 + p3;                         // 0.75+0.625u-3.25u^2+2.5u^3
    v2f u5 = u2 * u3;
    v2f hd = u5 * (-0.625f) + C;
    ha.x = fabsf(hd.x);
    ha.y = fabsf(hd.y);
}

// lane i <- lane i-1 (edge lane keeps self): DPP WAVE_SHR:1 = 0x138
__device__ __forceinline__ float dpp_left(float v) {
    int i = __float_as_int(v);
    return __int_as_float(
        __builtin_amdgcn_update_dpp(i, i, 0x138, 0xF, 0xF, false));
}
// lane i <- lane i+1 (edge lane keeps self): DPP WAVE_SHL:1 = 0x130
__device__ __forceinline__ float dpp_right(float v) {
    int i = __float_as_int(v);
    return __int_as_float(
        __builtin_amdgcn_update_dpp(i, i, 0x130, 0xF, 0xF, false));
}

// One LF step on 4 cells/lane held as P=(u0,u3), Q=(u1,u2).
__device__ __forceinline__ void lf_step(v2f& P, v2f& Q, float n[CPL],
                                        bool bcL, bool bcR, float dtdx) {
    v2f hfP, haP;
    eval2(P, hfP, haP);
    // halo exchange in the VALU pipe (DPP) — no DS op, no lgkmcnt wait
    float ul  = dpp_left(P.y);     // left neighbor's cell 3
    float hfl = dpp_left(hfP.y);
    float hal = dpp_left(haP.y);
    float ur  = dpp_right(P.x);    // right neighbor's cell 0
    float hfr = dpp_right(hfP.x);
    float har = dpp_right(haP.x);

    v2f hfQ, haQ;
    eval2(Q, hfQ, haQ);

    // 5 interface fluxes (0.5 pre-folded into hf/ha)
    float fh0 = (hfl   + hfP.x) - fmaxf(hal,   haP.x) * (P.x - ul);
    float fh1 = (hfP.x + hfQ.x) - fmaxf(haP.x, haQ.x) * (Q.x - P.x);
    float fh2 = (hfQ.x + hfQ.y) - fmaxf(haQ.x, haQ.y) * (Q.y - Q.x);
    float fh3 = (hfQ.y + hfP.y) - fmaxf(haQ.y, haP.y) * (P.y - Q.y);
    float fh4 = (hfP.y + hfr  ) - fmaxf(haP.y, har  ) * (ur  - P.y);

    n[0] = P.x - dtdx * (fh1 - fh0);
    n[1] = Q.x - dtdx * (fh2 - fh1);
    n[2] = Q.y - dtdx * (fh3 - fh2);
    n[3] = P.y - dtdx * (fh4 - fh3);

    // outflow BCs: u[0]=u[1], u[N-1]=u[N-2] (firewall against halo garbage)
    if (bcL) n[0] = n[1];
    if (bcR) n[3] = n[2];

    P.x = n[0]; P.y = n[3];
    Q.x = n[1]; Q.y = n[2];
}

__global__ __launch_bounds__(64) void lf_all(const float* __restrict__ init,
                                             float* __restrict__ out,
                                             int* __restrict__ flags,
                                             int total) {
    const int lane  = threadIdx.x;          // one wave per block
    const int wid   = blockIdx.x;
    const int chunk = wid & (CHUNKS - 1);
    const int row   = wid >> 5;             // CHUNKS == 32
    const int gbase = chunk * OWN - HALO;
    const int c0    = lane * CPL;

    const float dtdx = (float)(0.0009 / (10.0 / 4096.0));

    // clamped global indices of this lane's 4 window cells
    int gidx[CPL];
    #pragma unroll
    for (int j = 0; j < CPL; ++j) {
        int g = gbase + c0 + j;
        gidx[j] = min(max(g, 0), NCELL - 1);
    }

    v2f P, Q;
    {
        const float* ip = init + (size_t)row * NCELL;
        float u0 = ip[gidx[0]], u1 = ip[gidx[1]], u2 = ip[gidx[2]], u3 = ip[gidx[3]];
        P.x = u0; P.y = u3;
        Q.x = u1; Q.y = u2;
    }

    // owned cells [64,192) -> lanes 16..47 (all 4 cells contiguous)
    const bool owned = (lane >= 16) && (lane < 48);
    const bool bcL = (chunk == 0) && (lane == 16);            // global cell 0
    const bool bcR = (chunk == CHUNKS - 1) && (lane == 47);   // global cell N-1
    const bool hasL = (chunk > 0);
    const bool hasR = (chunk < CHUNKS - 1);

    int e = 0;
    for (int s = 0; s < total; s += KSTEP, ++e) {
        const int ns = (total - s) < KSTEP ? (total - s) : KSTEP;
        float* op = out + (size_t)(s + 1) * BN + (size_t)row * NCELL + (gbase + c0);

        int t = 0;
        // groups of 4 steps, stores batched per group
        for (; t + 4 <= ns; t += 4) {
            float b0[CPL], b1[CPL], b2[CPL], b3[CPL];
            lf_step(P, Q, b0, bcL, bcR, dtdx);
            lf_step(P, Q, b1, bcL, bcR, dtdx);
            lf_step(P, Q, b2, bcL, bcR, dtdx);
            lf_step(P, Q, b3, bcL, bcR, dtdx);
            if (owned) {
                *(float4*)(op)            = make_float4(b0[0], b0[1], b0[2], b0[3]);
                *(float4*)(op + BN)       = make_float4(b1[0], b1[1], b1[2], b1[3]);
                *(float4*)(op + 2 * BN)   = make_float4(b2[0], b2[1], b2[2], b2[3]);
                *(float4*)(op + 3 * BN)   = make_float4(b3[0], b3[1], b3[2], b3[3]);
            }
            op += 4 * BN;
        }
        for (; t < ns; ++t) {
            float n[CPL];
            lf_step(P, Q, n, bcL, bcR, dtdx);
            if (owned) *(float4*)op = make_float4(n[0], n[1], n[2], n[3]);
            op += BN;
        }

        // epoch boundary: publish, sync with chunk neighbors, refresh halo
        if (s + ns < total) {
            __threadfence();   // drain + make plane stores device-visible
            if (lane == 0)
                __hip_atomic_store(&flags[wid], e + 1,
                                   __ATOMIC_RELEASE, __HIP_MEMORY_SCOPE_AGENT);
            if (hasL) {
                while (__hip_atomic_load(&flags[wid - 1], __ATOMIC_ACQUIRE,
                                         __HIP_MEMORY_SCOPE_AGENT) < e + 1)
                    __builtin_amdgcn_s_sleep(1);
            }
            if (hasR) {
                while (__hip_atomic_load(&flags[wid + 1], __ATOMIC_ACQUIRE,
                                         __HIP_MEMORY_SCOPE_AGENT) < e + 1)
                    __builtin_amdgcn_s_sleep(1);
            }
            // halo lanes reload their 4 cells from the plane just completed
            // (written by neighbor waves; owned lanes keep registers)
            if (!owned) {
                const float* rp = out + (size_t)(s + ns) * BN + (size_t)row * NCELL;
                float u0 = rp[gidx[0]], u1 = rp[gidx[1]],
                      u2 = rp[gidx[2]], u3 = rp[gidx[3]];
                P.x = u0; P.y = u3;
                Q.x = u1; Q.y = u2;
            }
        }
    }
}

extern "C" void kernel_launch(void* const* d_in, const int* in_sizes, int n_in,
                              void* d_out, int out_size, void* d_ws, size_t ws_size,
                              hipStream_t stream) {
    const float* init = (const float*)d_in[0];
    float* out = (float*)d_out;
    int* flags = (int*)d_ws;

    int total = out_size / BN - 1;

    // zero the neighbor-sync flags (d_ws is poisoned 0xAA; re-zeroed every
    // call so replays are deterministic)
    hipMemsetAsync(d_ws, 0, NWAVES * sizeof(int), stream);

    // plane 0 = init
    hipMemcpyAsync(d_out, init, (size_t)BN * sizeof(float),
                   hipMemcpyDeviceToDevice, stream);

    dim3 grid(NWAVES);   // 1024 blocks x 1 wave (1/SIMD chip-wide), co-resident
    dim3 block(64);
    void* args[] = { (void*)&init, (void*)&out, (void*)&flags, (void*)&total };
    hipLaunchCooperativeKernel((const void*)lf_all, grid, block, args, 0, stream);
}

// Round 12
// 195.803 us; speedup vs baseline: 4.0861x; 4.0861x over previous
//
#include <hip/hip_runtime.h>

// Problem constants (match reference)
#define BATCHN 32
#define NCELL  4096
#define BN     (BATCHN * NCELL)

// Round 12: D=5 dispatches (KSTEP=120) at CPL=6, plane-0 store folded in.
// Model (R1-R11): dur = D*(OH + K) + memcpy; OH ~8-9us per dependent
// dispatch (graph barrier), K ~ issue-bound (R8: +1 wave/SIMD = +exactly
// its issue). R11 killed persistent kernels (flag/fence sync thrashes L2:
// 4.2GB refetch). Optimum of D*OH + D*K(D) is D=5:
//   CPL=6, CELLS=384, OWN=128, HALO=128, 32 chunks x 32 rows = 1024 waves
//   (1/SIMD preserved -- R5's mistake was halving wave count).
// 128 % 6 != 0 -> straddle lanes 21/42 store partial vectors (aligned,
// exact coverage verified). BCs: global cell 0 = lane21 j2, cell 4095 =
// lane42 j3. Dispatch 0 also stores plane 0 (replaces serialized memcpy).
constexpr int CPL    = 6;
constexpr int CELLS  = 64 * CPL;           // 384
constexpr int HALO   = 128;
constexpr int OWN    = CELLS - 2 * HALO;   // 128
constexpr int KSTEP  = 120;                // steps per launch (margin 8)
constexpr int CHUNKS = NCELL / OWN;        // 32

typedef float v2f __attribute__((ext_vector_type(2)));

// hf = 0.5*f_real(u), ha = 0.5*|f_real'(u)| — monomial expansion, 0.5
// pre-folded (verified vs reference at u=1: f=1,f'=0; u=0.5: f=0.710286,
// f'=1.085938). Flux uses 0.5*max(a,b) == max(0.5a,0.5b) exactly.
__device__ __forceinline__ void eval2(v2f u, v2f& hf, v2f& ha) {
    v2f u2 = u * u;
    v2f u3 = u2 * u;
    v2f p1 = u * 0.3125f + 0.75f;
    v2f A  = u * p1;                               // 0.75u + 0.3125u^2
    v2f p2 = u * 0.625f + (-1.0833333333333333f);  // -13/12 + 0.625u
    v2f B  = u3 * p2 + A;
    v2f u6 = u3 * u3;
    hf = u6 * (-0.10416666666666667f) + B;         // -5/48 u^6
    v2f p3 = u * 0.625f + 0.75f;
    v2f p4 = u * 2.5f + (-3.25f);
    v2f C  = u2 * p4 + p3;                         // 0.75+0.625u-3.25u^2+2.5u^3
    v2f u5 = u2 * u3;
    v2f hd = u5 * (-0.625f) + C;
    ha.x = fabsf(hd.x);
    ha.y = fabsf(hd.y);
}

// lane i <- lane i-1 (edge lane keeps self): DPP WAVE_SHR:1 = 0x138
__device__ __forceinline__ float dpp_left(float v) {
    int i = __float_as_int(v);
    return __int_as_float(
        __builtin_amdgcn_update_dpp(i, i, 0x138, 0xF, 0xF, false));
}
// lane i <- lane i+1 (edge lane keeps self): DPP WAVE_SHL:1 = 0x130
__device__ __forceinline__ float dpp_right(float v) {
    int i = __float_as_int(v);
    return __int_as_float(
        __builtin_amdgcn_update_dpp(i, i, 0x130, 0xF, 0xF, false));
}

// One LF step on 6 cells/lane: P=(u0,u5) edge pair, Q=(u1,u2), R=(u3,u4).
__device__ __forceinline__ void lf_step(v2f& P, v2f& Q, v2f& R, float n[CPL],
                                        bool bcL, bool bcR, float dtdx) {
    v2f hfP, haP;
    eval2(P, hfP, haP);
    // halo exchange in the VALU pipe (DPP) — no DS op, no lgkmcnt wait
    float ul  = dpp_left(P.y);     // left neighbor's cell 5
    float hfl = dpp_left(hfP.y);
    float hal = dpp_left(haP.y);
    float ur  = dpp_right(P.x);    // right neighbor's cell 0
    float hfr = dpp_right(hfP.x);
    float har = dpp_right(haP.x);

    v2f hfQ, haQ, hfR, haR;
    eval2(Q, hfQ, haQ);
    eval2(R, hfR, haR);

    // 7 interface fluxes (0.5 pre-folded into hf/ha)
    float fh0 = (hfl   + hfP.x) - fmaxf(hal,   haP.x) * (P.x - ul);
    float fh1 = (hfP.x + hfQ.x) - fmaxf(haP.x, haQ.x) * (Q.x - P.x);
    float fh2 = (hfQ.x + hfQ.y) - fmaxf(haQ.x, haQ.y) * (Q.y - Q.x);
    float fh3 = (hfQ.y + hfR.x) - fmaxf(haQ.y, haR.x) * (R.x - Q.y);
    float fh4 = (hfR.x + hfR.y) - fmaxf(haR.x, haR.y) * (R.y - R.x);
    float fh5 = (hfR.y + hfP.y) - fmaxf(haR.y, haP.y) * (P.y - R.y);
    float fh6 = (hfP.y + hfr  ) - fmaxf(haP.y, har  ) * (ur  - P.y);

    n[0] = P.x - dtdx * (fh1 - fh0);
    n[1] = Q.x - dtdx * (fh2 - fh1);
    n[2] = Q.y - dtdx * (fh3 - fh2);
    n[3] = R.x - dtdx * (fh4 - fh3);
    n[4] = R.y - dtdx * (fh5 - fh4);
    n[5] = P.y - dtdx * (fh6 - fh5);

    // outflow BCs at physical edges (firewall against halo garbage):
    // global cell 0 = chunk0 lane21 j2; global cell N-1 = chunk31 lane42 j3
    if (bcL) n[2] = n[3];
    if (bcR) n[3] = n[2];

    P.x = n[0]; P.y = n[5];
    Q.x = n[1]; Q.y = n[2];
    R.x = n[3]; R.y = n[4];
}

// Store this lane's owned cells of one plane.
//  sB (lanes 22..41): all 6 cells -> float4 @c0 + float2 @c0+4
//  sA (lane 21): cells j=2..5 (global 128..131 local) -> float4 @c0+2
//  sC (lane 42): cells j=0..3 -> float4 @c0
__device__ __forceinline__ void store_plane(float* op, const float b[CPL],
                                            bool sA, bool sB, bool sC) {
    if (sB) {
        *(float4*)op       = make_float4(b[0], b[1], b[2], b[3]);
        *(float2*)(op + 4) = make_float2(b[4], b[5]);
    } else if (sA) {
        *(float4*)(op + 2) = make_float4(b[2], b[3], b[4], b[5]);
    } else if (sC) {
        *(float4*)op       = make_float4(b[0], b[1], b[2], b[3]);
    }
}

__global__ __launch_bounds__(64) void lf_wave(const float* __restrict__ in_state,
                                              float* __restrict__ out,
                                              int s0, int nsteps) {
    const int lane  = threadIdx.x;          // one wave per block
    const int wid   = blockIdx.x;
    const int chunk = wid & (CHUNKS - 1);
    const int row   = wid >> 5;             // CHUNKS == 32
    const int gbase = chunk * OWN - HALO;
    const int c0    = lane * CPL;

    const float dtdx = (float)(0.0009 / (10.0 / 4096.0));

    float uin[CPL];
    {
        const float* ip = in_state + (size_t)row * NCELL;
        #pragma unroll
        for (int j = 0; j < CPL; ++j) {
            int g = gbase + c0 + j;
            g = min(max(g, 0), NCELL - 1);
            uin[j] = ip[g];
        }
    }
    v2f P, Q, R;
    P.x = uin[0]; P.y = uin[5];
    Q.x = uin[1]; Q.y = uin[2];
    R.x = uin[3]; R.y = uin[4];

    // ownership within owned region [128,256) local:
    const bool sA = (lane == 21);                 // straddle left (j>=2 owned)
    const bool sB = (lane >= 22) && (lane <= 41); // fully owned
    const bool sC = (lane == 42);                 // straddle right (j<=3 owned)
    const bool bcL = (chunk == 0) && sA;              // global cell 0 at j=2
    const bool bcR = (chunk == CHUNKS - 1) && sC;     // global cell N-1 at j=3

    float* op = out + (size_t)(s0 + 1) * BN + (size_t)row * NCELL + (gbase + c0);

    // dispatch 0: also write plane 0 (= init), replacing the d2d memcpy
    if (s0 == 0) {
        store_plane(op - BN, uin, sA, sB, sC);
    }

    int t = 0;
    // groups of 4 steps, stores batched per group
    for (; t + 4 <= nsteps; t += 4) {
        float b0[CPL], b1[CPL], b2[CPL], b3[CPL];
        lf_step(P, Q, R, b0, bcL, bcR, dtdx);
        lf_step(P, Q, R, b1, bcL, bcR, dtdx);
        lf_step(P, Q, R, b2, bcL, bcR, dtdx);
        lf_step(P, Q, R, b3, bcL, bcR, dtdx);
        store_plane(op,          b0, sA, sB, sC);
        store_plane(op + BN,     b1, sA, sB, sC);
        store_plane(op + 2 * BN, b2, sA, sB, sC);
        store_plane(op + 3 * BN, b3, sA, sB, sC);
        op += 4 * BN;
    }
    // tail (not hit for nsteps=120, kept for robustness)
    for (; t < nsteps; ++t) {
        float n[CPL];
        lf_step(P, Q, R, n, bcL, bcR, dtdx);
        store_plane(op, n, sA, sB, sC);
        op += BN;
    }
}

extern "C" void kernel_launch(void* const* d_in, const int* in_sizes, int n_in,
                              void* d_out, int out_size, void* d_ws, size_t ws_size,
                              hipStream_t stream) {
    const float* init = (const float*)d_in[0];
    float* out = (float*)d_out;

    const int total = out_size / BN - 1;

    const int nblocks = CHUNKS * BATCHN;    // 1024 waves, 1/SIMD chip-wide
    for (int s = 0; s < total; s += KSTEP) {
        int ns = (total - s) < KSTEP ? (total - s) : KSTEP;
        const float* src = (s == 0) ? init : out + (size_t)s * BN;
        lf_wave<<<nblocks, 64, 0, stream>>>(src, out, s, ns);
    }
}

// Round 13
// 150.019 us; speedup vs baseline: 5.3331x; 1.3052x over previous
//
#include <hip/hip_runtime.h>

// Problem constants (match reference)
#define BATCHN 32
#define NCELL  4096
#define BN     (BATCHN * NCELL)

// Round 13: R10 + 12-deep rotating store buffers (reuse distance 4->12
// steps) with stores issued per-step (smooth), + plane-0 store folded into
// dispatch 0 (drops the serialized d2d memcpy).
// Model: R10/R12 joint fit gives OH~3us/dispatch and ~8.3 cyc/inst
// effective in-kernel (4x the 2cyc issue floor) at every CPL. Suspected
// hidden term: vmcnt waits before REUSING store-data registers -- 4-deep
// buffers are rewritten ~1900cyc after their stores issue; if HBM
// store-ack > that, every group stalls. 12-deep (~5800cyc) clears it.
constexpr int OWN    = 128;
constexpr int HALO   = 64;
constexpr int CPL    = 4;                  // cells per lane
constexpr int KSTEP  = 60;                 // steps per launch (< HALO)
constexpr int CHUNKS = NCELL / OWN;        // 32

typedef float v2f __attribute__((ext_vector_type(2)));

// hf = 0.5*f_real(u), ha = 0.5*|f_real'(u)| — monomial expansion, 0.5
// pre-folded (verified vs reference at u=1: f=1,f'=0; u=0.5: f=0.710286,
// f'=1.085938). Flux uses 0.5*max(a,b) == max(0.5a,0.5b) exactly.
__device__ __forceinline__ void eval2(v2f u, v2f& hf, v2f& ha) {
    v2f u2 = u * u;
    v2f u3 = u2 * u;
    v2f p1 = u * 0.3125f + 0.75f;
    v2f A  = u * p1;                               // 0.75u + 0.3125u^2
    v2f p2 = u * 0.625f + (-1.0833333333333333f);  // -13/12 + 0.625u
    v2f B  = u3 * p2 + A;
    v2f u6 = u3 * u3;
    hf = u6 * (-0.10416666666666667f) + B;         // -5/48 u^6
    v2f p3 = u * 0.625f + 0.75f;
    v2f p4 = u * 2.5f + (-3.25f);
    v2f C  = u2 * p4 + p3;                         // 0.75+0.625u-3.25u^2+2.5u^3
    v2f u5 = u2 * u3;
    v2f hd = u5 * (-0.625f) + C;
    ha.x = fabsf(hd.x);
    ha.y = fabsf(hd.y);
}

// lane i <- lane i-1 (edge lane keeps self): DPP WAVE_SHR:1 = 0x138
__device__ __forceinline__ float dpp_left(float v) {
    int i = __float_as_int(v);
    return __int_as_float(
        __builtin_amdgcn_update_dpp(i, i, 0x138, 0xF, 0xF, false));
}
// lane i <- lane i+1 (edge lane keeps self): DPP WAVE_SHL:1 = 0x130
__device__ __forceinline__ float dpp_right(float v) {
    int i = __float_as_int(v);
    return __int_as_float(
        __builtin_amdgcn_update_dpp(i, i, 0x130, 0xF, 0xF, false));
}

// One LF step on 4 cells/lane held as P=(u0,u3), Q=(u1,u2).
__device__ __forceinline__ void lf_step(v2f& P, v2f& Q, float n[CPL],
                                        bool bcL, bool bcR, float dtdx) {
    v2f hfP, haP;
    eval2(P, hfP, haP);
    // halo exchange in the VALU pipe (DPP) — no DS op, no lgkmcnt wait
    float ul  = dpp_left(P.y);     // left neighbor's cell 3
    float hfl = dpp_left(hfP.y);
    float hal = dpp_left(haP.y);
    float ur  = dpp_right(P.x);    // right neighbor's cell 0
    float hfr = dpp_right(hfP.x);
    float har = dpp_right(haP.x);

    v2f hfQ, haQ;
    eval2(Q, hfQ, haQ);

    // 5 interface fluxes (0.5 pre-folded into hf/ha)
    float fh0 = (hfl   + hfP.x) - fmaxf(hal,   haP.x) * (P.x - ul);
    float fh1 = (hfP.x + hfQ.x) - fmaxf(haP.x, haQ.x) * (Q.x - P.x);
    float fh2 = (hfQ.x + hfQ.y) - fmaxf(haQ.x, haQ.y) * (Q.y - Q.x);
    float fh3 = (hfQ.y + hfP.y) - fmaxf(haQ.y, haP.y) * (P.y - Q.y);
    float fh4 = (hfP.y + hfr  ) - fmaxf(haP.y, har  ) * (ur  - P.y);

    n[0] = P.x - dtdx * (fh1 - fh0);
    n[1] = Q.x - dtdx * (fh2 - fh1);
    n[2] = Q.y - dtdx * (fh3 - fh2);
    n[3] = P.y - dtdx * (fh4 - fh3);

    // outflow BCs: u[0]=u[1], u[N-1]=u[N-2] (firewall against halo garbage)
    if (bcL) n[0] = n[1];
    if (bcR) n[3] = n[2];

    P.x = n[0]; P.y = n[3];
    Q.x = n[1]; Q.y = n[2];
}

__global__ __launch_bounds__(64) void lf_wave(const float* __restrict__ in_state,
                                              float* __restrict__ out,
                                              int s0, int nsteps) {
    const int lane  = threadIdx.x;          // one wave per block
    const int wid   = blockIdx.x;
    const int chunk = wid & (CHUNKS - 1);
    const int row   = wid >> 5;             // CHUNKS == 32
    const int gbase = chunk * OWN - HALO;
    const int c0    = lane * CPL;

    const float dtdx = (float)(0.0009 / (10.0 / 4096.0));

    float uin[CPL];
    {
        const float* ip = in_state + (size_t)row * NCELL;
        #pragma unroll
        for (int j = 0; j < CPL; ++j) {
            int g = gbase + c0 + j;
            g = min(max(g, 0), NCELL - 1);
            uin[j] = ip[g];
        }
    }
    v2f P, Q;
    P.x = uin[0]; P.y = uin[3];
    Q.x = uin[1]; Q.y = uin[2];

    // owned cells [64,192) -> lanes 16..47 (all 4 cells contiguous)
    const bool owned = (lane >= 16) && (lane < 48);
    const bool bcL = (chunk == 0) && (lane == 16);            // global cell 0
    const bool bcR = (chunk == CHUNKS - 1) && (lane == 47);   // global cell N-1

    float* op = out + (size_t)(s0 + 1) * BN + (size_t)row * NCELL + (gbase + c0);

    // dispatch 0: write plane 0 (= init), replacing the d2d memcpy
    if (s0 == 0 && owned) {
        *(float4*)(op - BN) = make_float4(uin[0], uin[1], uin[2], uin[3]);
    }

    // one step + immediate store into rotating buffer B (reuse dist 12)
#define STEP_STORE(B, K)                                                  \
    lf_step(P, Q, B, bcL, bcR, dtdx);                                     \
    if (owned) *(float4*)(op + (K) * BN) = make_float4(B[0], B[1], B[2], B[3]);

    int t = 0;
    for (; t + 12 <= nsteps; t += 12) {
        float c0b[CPL], c1b[CPL], c2b[CPL], c3b[CPL], c4b[CPL], c5b[CPL];
        float c6b[CPL], c7b[CPL], c8b[CPL], c9b[CPL], c10b[CPL], c11b[CPL];
        STEP_STORE(c0b, 0)
        STEP_STORE(c1b, 1)
        STEP_STORE(c2b, 2)
        STEP_STORE(c3b, 3)
        STEP_STORE(c4b, 4)
        STEP_STORE(c5b, 5)
        STEP_STORE(c6b, 6)
        STEP_STORE(c7b, 7)
        STEP_STORE(c8b, 8)
        STEP_STORE(c9b, 9)
        STEP_STORE(c10b, 10)
        STEP_STORE(c11b, 11)
        op += 12 * BN;
    }
    // tail (not hit for nsteps=60, kept for robustness)
    for (; t < nsteps; ++t) {
        float n[CPL];
        lf_step(P, Q, n, bcL, bcR, dtdx);
        if (owned) *(float4*)op = make_float4(n[0], n[1], n[2], n[3]);
        op += BN;
    }
#undef STEP_STORE
}

extern "C" void kernel_launch(void* const* d_in, const int* in_sizes, int n_in,
                              void* d_out, int out_size, void* d_ws, size_t ws_size,
                              hipStream_t stream) {
    const float* init = (const float*)d_in[0];
    float* out = (float*)d_out;

    const int total = out_size / BN - 1;

    const int nblocks = CHUNKS * BATCHN;    // 1024 waves, 1/SIMD chip-wide
    for (int s = 0; s < total; s += KSTEP) {
        int ns = (total - s) < KSTEP ? (total - s) : KSTEP;
        const float* src = (s == 0) ? init : out + (size_t)s * BN;
        lf_wave<<<nblocks, 64, 0, stream>>>(src, out, s, ns);
    }
}